// Round 1
// baseline (514.045 us; speedup 1.0000x reference)
//
#include <hip/hip_runtime.h>
#include <stdint.h>

typedef unsigned short u16;
typedef u16 u16x8 __attribute__((ext_vector_type(8)));
typedef u16x8 __attribute__((may_alias)) u16x8a;
typedef float f32x4 __attribute__((ext_vector_type(4)));
typedef f32x4 __attribute__((may_alias)) f32x4a;
typedef __bf16 bf16x8 __attribute__((ext_vector_type(8)));
typedef float f32x16 __attribute__((ext_vector_type(16)));

#define S_LEN 1024
#define D_DIM 64
#define BHN   64

// f32 -> bf16 via compiler cast: gfx950 emits v_cvt_pk_bf16_f32 (RNE, same
// rounding as the old software f2bf, ~5x fewer VALU ops).
__device__ __forceinline__ bf16x8 cvt8(const float* p) {
  f32x4 a = *reinterpret_cast<const f32x4a*>(p);
  f32x4 b = *reinterpret_cast<const f32x4a*>(p + 4);
  bf16x8 r;
#pragma unroll
  for (int j = 0; j < 4; ++j) { r[j] = (__bf16)a[j]; r[4 + j] = (__bf16)b[j]; }
  return r;
}
__device__ __forceinline__ bf16x8 ldbf(const u16* p) {
  return __builtin_bit_cast(bf16x8, *reinterpret_cast<const u16x8a*>(p));
}

// ---------------- fused attention (fp32 in / fp32 out, bf16 MFMA inside) -------------
// block: 256 thr = 4 waves, one (bh, 32-row q tile). wave w owns k-cols [256w,256w+256).
// LDS (no aliasing):
//   [0, 20480)      ping-pong P-bounce tiles [2][4][32][40] u16 (per-wave, fence-only)
//   [20480, 29184)  O-reduce accumulator [32][68] f32 (ds_add_f32 atomics)
//   [29184, 29696)  rowsum [4][32] f32
//   [29696, 29824)  inv [32] f32
#define ORED_OFF   20480
#define RS_OFF     (ORED_OFF + 32 * 68 * 4)
#define INV_OFF    (RS_OFF + 512)
#define SMEM_BYTES (INV_OFF + 128)

__global__ __launch_bounds__(256, 4) void attn_kernel(
    const float* __restrict__ Q, const float* __restrict__ K, const int* __restrict__ Mk,
    const float* __restrict__ V, float* __restrict__ outO, float* __restrict__ outA) {
  __shared__ __align__(16) char smem[SMEM_BYTES];
  const int tid = threadIdx.x;
  const int wave = tid >> 6, lane = tid & 63;
  const int l31 = lane & 31, half = lane >> 5;

  // XCD swizzle: ids congruent mod 8 share an XCD (round-robin dispatch).
  // Make the 32 q-tiles of ONE bh time-contiguous on one XCD so K/V (512 KB)
  // stay L2-resident instead of 8 bh (4 MB = whole L2) thrashing.
  const int id = blockIdx.x;                  // 0..2047
  const int xcd = id & 7, ord = id >> 3;      // ord: temporal order within XCD
  const int bh = xcd * 8 + (ord >> 5);
  const int q0 = (ord & 31) << 5;             // q-tile * 32

  u16* tbase = (u16*)smem;                    // ping-pong bounce tiles
  float* ored = (float*)(smem + ORED_OFF);    // [32][68] atomic O accumulator
  float* rs_lds = (float*)(smem + RS_OFF);    // [4][32]
  float* inv_lds = (float*)(smem + INV_OFF);  // [32]

  // zero the O accumulator (ordered before any ds_add by the rowsum barrier)
  for (int i = tid; i < 32 * 68; i += 256) ored[i] = 0.0f;

  // ---- Q A-fragments: lane holds Q[q0+l31][ks*16 + half*8 + j] (fp32 -> bf16) ----
  const float* qb = Q + (((size_t)bh << 10) + q0 + l31) * D_DIM + half * 8;
  bf16x8 qa[4];
#pragma unroll
  for (int ks = 0; ks < 4; ++ks) qa[ks] = cvt8(qb + ks * 16);

  const int colbase = wave * 256;
  const float* kb0 = K + ((size_t)bh << 10) * D_DIM + half * 8;
  const int* mrow = Mk + ((size_t)bh << 10) + colbase + l31;

  bf16x8 pfrag[16];  // wave's unnormalized exp(P) chunk [32 x 256] as A-frags
  float rs[16];
#pragma unroll
  for (int r = 0; r < 16; ++r) rs[r] = 0.0f;

  // ---- phase 1: QK^T -> exp -> A-layout frags. Bounce tile is PER-WAVE, so a
  // per-wave lgkmcnt fence replaces the old per-t __syncthreads (no 4-wave
  // lockstep, no vmcnt(0) drain of in-flight K loads).
#pragma unroll
  for (int t = 0; t < 8; ++t) {
    u16* tile = tbase + (((t & 1) << 2) + wave) * (32 * 40);
    const float* kb = kb0 + (size_t)(colbase + t * 32 + l31) * D_DIM;
    f32x16 acc = 0.0f;
#pragma unroll
    for (int ks = 0; ks < 4; ++ks) {
      bf16x8 kf = cvt8(kb + ks * 16);
      acc = __builtin_amdgcn_mfma_f32_32x32x16_bf16(qa[ks], kf, acc, 0, 0, 0);
    }
    const float mf = (mrow[t * 32] == 0) ? 0.0f : 1.0f;
#pragma unroll
    for (int r = 0; r < 16; ++r) {
      // score = acc/8 ; exp(score) = exp2(acc * 0.125*log2(e)); no max-sub needed
      float p = exp2f(acc[r] * 0.18033688f) * mf;
      __bf16 pb = (__bf16)p;
      rs[r] += (float)pb;  // bf16-consistent numerator/denominator
      const int row = (r & 3) + ((r >> 2) << 3) + (half << 2);  // C-layout row
      tile[row * 40 + l31] = __builtin_bit_cast(u16, pb);
    }
    // per-wave fence: bounce write -> bounce read (WAR across t handled by ping-pong)
    asm volatile("s_waitcnt lgkmcnt(0)" ::: "memory");
    __builtin_amdgcn_sched_barrier(0);
    pfrag[2 * t]     = ldbf(tile + l31 * 40 + half * 8);
    pfrag[2 * t + 1] = ldbf(tile + l31 * 40 + 16 + half * 8);
  }

  // ---- row sums: butterfly within 32-lane half, then cross-wave via LDS ----
#pragma unroll
  for (int r = 0; r < 16; ++r) {
    float s = rs[r];
#pragma unroll
    for (int m = 1; m < 32; m <<= 1) s += __shfl_xor(s, m, 64);
    rs[r] = s;
  }
  if (l31 == 0) {
#pragma unroll
    for (int r = 0; r < 16; ++r) {
      const int row = (r & 3) + ((r >> 2) << 3) + (half << 2);
      rs_lds[wave * 32 + row] = rs[r];
    }
  }
  __syncthreads();
  if (tid < 32) {
    float s = rs_lds[tid] + rs_lds[32 + tid] + rs_lds[64 + tid] + rs_lds[96 + tid];
    inv_lds[tid] = 1.0f / s;
  }
  __syncthreads();

  // ---- PV + interleaved attn store: spreads the 128 KB/block of attn writes
  // across the V loads and MFMAs instead of a post-hoc burst. B-frags scalar-
  // loaded straight from global V (L2-resident with the new swizzle).
  const float myinv = inv_lds[l31];
  float* ab = outA + ((size_t)bh << 20) + ((size_t)(q0 + l31) << 10) + colbase + half * 8;
  const float* vb = V + (((size_t)bh << 10) + colbase + half * 8) * D_DIM + l31;
  f32x16 oacc0 = 0.0f, oacc1 = 0.0f;
#pragma unroll
  for (int kk = 0; kk < 16; ++kk) {
    bf16x8 b0, b1;
#pragma unroll
    for (int jj = 0; jj < 8; ++jj) {
      b0[jj] = (__bf16)vb[(kk * 16 + jj) * D_DIM];
      b1[jj] = (__bf16)vb[(kk * 16 + jj) * D_DIM + 32];
    }
    oacc0 = __builtin_amdgcn_mfma_f32_32x32x16_bf16(pfrag[kk], b0, oacc0, 0, 0, 0);
    oacc1 = __builtin_amdgcn_mfma_f32_32x32x16_bf16(pfrag[kk], b1, oacc1, 0, 0, 0);
    // normalized attn write for this fragment (32B/lane runs)
    f32x4 lo, hi;
#pragma unroll
    for (int jj = 0; jj < 4; ++jj) {
      lo[jj] = (float)pfrag[kk][jj] * myinv;
      hi[jj] = (float)pfrag[kk][4 + jj] * myinv;
    }
    float* dst = ab + (kk >> 1) * 32 + (kk & 1) * 16;
    *reinterpret_cast<f32x4a*>(dst) = lo;
    *reinterpret_cast<f32x4a*>(dst + 4) = hi;
  }

  // ---- cross-wave O reduction via LDS float atomics (bank-conflict-free:
  // stride 68 words; halves land on disjoint bank sets) ----
#pragma unroll
  for (int r = 0; r < 16; ++r) {
    const int row = (r & 3) + ((r >> 2) << 3) + (half << 2);
    atomicAdd(&ored[row * 68 + l31], oacc0[r]);
    atomicAdd(&ored[row * 68 + 32 + l31], oacc1[r]);
  }
  // lgkm-only barrier: do NOT drain vmcnt, the outstanding attn stores can
  // retire while the tiny O epilogue runs.
  asm volatile("s_waitcnt lgkmcnt(0)" ::: "memory");
  __builtin_amdgcn_s_barrier();
  __builtin_amdgcn_sched_barrier(0);

  const int orow = tid >> 3;
  const int oc = (tid & 7) * 8;
  const float iv = inv_lds[orow];
  f32x4 o0 = *reinterpret_cast<const f32x4a*>(ored + orow * 68 + oc);
  f32x4 o1 = *reinterpret_cast<const f32x4a*>(ored + orow * 68 + oc + 4);
#pragma unroll
  for (int jj = 0; jj < 4; ++jj) { o0[jj] *= iv; o1[jj] *= iv; }
  float* ob = outO + (((size_t)bh << 10) + q0 + orow) * D_DIM + oc;
  *reinterpret_cast<f32x4a*>(ob) = o0;
  *reinterpret_cast<f32x4a*>(ob + 4) = o1;
}

extern "C" void kernel_launch(void* const* d_in, const int* in_sizes, int n_in,
                              void* d_out, int out_size, void* d_ws, size_t ws_size,
                              hipStream_t stream) {
  (void)in_sizes; (void)n_in; (void)out_size; (void)d_ws; (void)ws_size;
  const float* Q = (const float*)d_in[0];
  const float* K = (const float*)d_in[1];
  const float* V = (const float*)d_in[2];
  const int*   M = (const int*)d_in[3];
  float* outO = (float*)d_out;
  float* outA = outO + (size_t)BHN * S_LEN * D_DIM;  // attn follows output, flat

  attn_kernel<<<dim3(BHN * (S_LEN / 32)), dim3(256), 0, stream>>>(Q, K, M, V, outO, outA);
}

// Round 2
// 506.070 us; speedup vs baseline: 1.0158x; 1.0158x over previous
//
#include <hip/hip_runtime.h>
#include <stdint.h>

typedef unsigned short u16;
typedef u16 u16x8 __attribute__((ext_vector_type(8)));
typedef u16x8 __attribute__((may_alias)) u16x8a;
typedef float f32x4 __attribute__((ext_vector_type(4)));
typedef f32x4 __attribute__((may_alias)) f32x4a;
typedef __bf16 bf16x8 __attribute__((ext_vector_type(8)));
typedef float f32x16 __attribute__((ext_vector_type(16)));

#define S_LEN 1024
#define D_DIM 64
#define BHN   64

// f32 -> bf16 via compiler cast: gfx950 emits v_cvt_pk_bf16_f32 (RNE, same
// rounding as software round-to-nearest-even bit-twiddle).
__device__ __forceinline__ bf16x8 cvt8(const float* p) {
  f32x4 a = *reinterpret_cast<const f32x4a*>(p);
  f32x4 b = *reinterpret_cast<const f32x4a*>(p + 4);
  bf16x8 r;
#pragma unroll
  for (int j = 0; j < 4; ++j) { r[j] = (__bf16)a[j]; r[4 + j] = (__bf16)b[j]; }
  return r;
}
__device__ __forceinline__ bf16x8 ldbf(const u16* p) {
  return __builtin_bit_cast(bf16x8, *reinterpret_cast<const u16x8a*>(p));
}

// ---------------- fused attention (fp32 in / fp32 out, bf16 MFMA inside) -------------
// block: 256 thr = 4 waves, one (bh, 32-row q tile). wave w owns k-cols [256w,256w+256).
// LDS (no aliasing):
//   [0, 20480)      ping-pong P-bounce tiles [2][4][32][40] u16 (per-wave, fence-only)
//   [20480, 29184)  O-reduce accumulator [32][68] f32 (ds_add_f32 atomics)
//   [29184, 29696)  rowsum [4][32] f32
//   [29696, 29824)  inv [32] f32
#define ORED_OFF   20480
#define RS_OFF     (ORED_OFF + 32 * 68 * 4)
#define INV_OFF    (RS_OFF + 512)
#define SMEM_BYTES (INV_OFF + 128)

// (256,3): live state is ~112 regs/lane (pfrag 64 + qa 16 + oacc 32 AGPR) +
// temps. Forcing 4 blocks/CU (<=128) spills to scratch: R1 measured +88 MB
// write traffic and 187->262 us. 3 blocks/CU spill-free is strictly better.
__global__ __launch_bounds__(256, 3) void attn_kernel(
    const float* __restrict__ Q, const float* __restrict__ K, const int* __restrict__ Mk,
    const float* __restrict__ V, float* __restrict__ outO, float* __restrict__ outA) {
  __shared__ __align__(16) char smem[SMEM_BYTES];
  const int tid = threadIdx.x;
  const int wave = tid >> 6, lane = tid & 63;
  const int l31 = lane & 31, half = lane >> 5;

  // XCD swizzle: ids congruent mod 8 share an XCD (round-robin dispatch).
  // The 32 q-tiles of ONE bh are time-contiguous on one XCD so K/V (512 KB)
  // stay L2-resident (R1: FETCH 122 -> 92 MB vs round-0 swizzle).
  const int id = blockIdx.x;                  // 0..2047
  const int xcd = id & 7, ord = id >> 3;      // ord: temporal order within XCD
  const int bh = xcd * 8 + (ord >> 5);
  const int q0 = (ord & 31) << 5;             // q-tile * 32

  u16* tbase = (u16*)smem;                    // ping-pong bounce tiles
  float* ored = (float*)(smem + ORED_OFF);    // [32][68] atomic O accumulator
  float* rs_lds = (float*)(smem + RS_OFF);    // [4][32]
  float* inv_lds = (float*)(smem + INV_OFF);  // [32]

  // zero the O accumulator (ordered before any ds_add by the rowsum barrier)
  for (int i = tid; i < 32 * 68; i += 256) ored[i] = 0.0f;

  // ---- Q A-fragments: lane holds Q[q0+l31][ks*16 + half*8 + j] (fp32 -> bf16) ----
  const float* qb = Q + (((size_t)bh << 10) + q0 + l31) * D_DIM + half * 8;
  bf16x8 qa[4];
#pragma unroll
  for (int ks = 0; ks < 4; ++ks) qa[ks] = cvt8(qb + ks * 16);

  const int colbase = wave * 256;
  const float* kb0 = K + ((size_t)bh << 10) * D_DIM + half * 8;
  const int* mrow = Mk + ((size_t)bh << 10) + colbase + l31;

  bf16x8 pfrag[16];  // wave's unnormalized exp(P) chunk [32 x 256] as A-frags
  float rs[16];
#pragma unroll
  for (int r = 0; r < 16; ++r) rs[r] = 0.0f;

  // ---- phase 1: QK^T -> exp -> A-layout frags. Bounce tile is PER-WAVE, so a
  // per-wave lgkmcnt fence replaces a __syncthreads (no 4-wave lockstep, no
  // vmcnt(0) drain of in-flight K loads).
#pragma unroll
  for (int t = 0; t < 8; ++t) {
    u16* tile = tbase + (((t & 1) << 2) + wave) * (32 * 40);
    const float* kb = kb0 + (size_t)(colbase + t * 32 + l31) * D_DIM;
    f32x16 acc = 0.0f;
#pragma unroll
    for (int ks = 0; ks < 4; ++ks) {
      bf16x8 kf = cvt8(kb + ks * 16);
      acc = __builtin_amdgcn_mfma_f32_32x32x16_bf16(qa[ks], kf, acc, 0, 0, 0);
    }
    const float mf = (mrow[t * 32] == 0) ? 0.0f : 1.0f;
#pragma unroll
    for (int r = 0; r < 16; ++r) {
      // score = acc/8 ; exp(score) = exp2(acc * 0.125*log2(e)); no max-sub needed
      float p = exp2f(acc[r] * 0.18033688f) * mf;
      __bf16 pb = (__bf16)p;
      rs[r] += (float)pb;  // bf16-consistent numerator/denominator
      const int row = (r & 3) + ((r >> 2) << 3) + (half << 2);  // C-layout row
      tile[row * 40 + l31] = __builtin_bit_cast(u16, pb);
    }
    // per-wave fence: bounce write -> bounce read (WAR across t handled by ping-pong)
    asm volatile("s_waitcnt lgkmcnt(0)" ::: "memory");
    __builtin_amdgcn_sched_barrier(0);
    pfrag[2 * t]     = ldbf(tile + l31 * 40 + half * 8);
    pfrag[2 * t + 1] = ldbf(tile + l31 * 40 + 16 + half * 8);
  }

  // ---- row sums: butterfly within 32-lane half, then cross-wave via LDS ----
#pragma unroll
  for (int r = 0; r < 16; ++r) {
    float s = rs[r];
#pragma unroll
    for (int m = 1; m < 32; m <<= 1) s += __shfl_xor(s, m, 64);
    rs[r] = s;
  }
  if (l31 == 0) {
#pragma unroll
    for (int r = 0; r < 16; ++r) {
      const int row = (r & 3) + ((r >> 2) << 3) + (half << 2);
      rs_lds[wave * 32 + row] = rs[r];
    }
  }
  __syncthreads();
  if (tid < 32) {
    float s = rs_lds[tid] + rs_lds[32 + tid] + rs_lds[64 + tid] + rs_lds[96 + tid];
    inv_lds[tid] = 1.0f / s;
  }
  __syncthreads();

  // ---- PV: O_partial[32x64]; B-frags scalar-loaded straight from global V
  // (L2-resident with the swizzle). No stores inside this loop: keeps the MFMA
  // loop's register/addressing footprint minimal.
  f32x16 oacc0 = 0.0f, oacc1 = 0.0f;
  const float* vb = V + (((size_t)bh << 10) + colbase + half * 8) * D_DIM + l31;
#pragma unroll
  for (int kk = 0; kk < 16; ++kk) {
    bf16x8 b0, b1;
#pragma unroll
    for (int jj = 0; jj < 8; ++jj) {
      b0[jj] = (__bf16)vb[(kk * 16 + jj) * D_DIM];
      b1[jj] = (__bf16)vb[(kk * 16 + jj) * D_DIM + 32];
    }
    oacc0 = __builtin_amdgcn_mfma_f32_32x32x16_bf16(pfrag[kk], b0, oacc0, 0, 0, 0);
    oacc1 = __builtin_amdgcn_mfma_f32_32x32x16_bf16(pfrag[kk], b1, oacc1, 0, 0, 0);
  }

  // ---- attn write (fp32): direct from A-layout registers, 32B/lane runs.
  // Nontemporal: 268 MB stream, never re-read -> don't thrash L2 (K/V stay hot).
  const float myinv = inv_lds[l31];
  float* ab = outA + ((size_t)bh << 20) + ((size_t)(q0 + l31) << 10) + colbase + half * 8;
#pragma unroll
  for (int t = 0; t < 8; ++t) {
#pragma unroll
    for (int f = 0; f < 2; ++f) {
      bf16x8 pf = pfrag[2 * t + f];
      f32x4 lo, hi;
#pragma unroll
      for (int j = 0; j < 4; ++j) {
        lo[j] = (float)pf[j] * myinv;
        hi[j] = (float)pf[4 + j] * myinv;
      }
      __builtin_nontemporal_store(lo, reinterpret_cast<f32x4a*>(ab + t * 32 + f * 16));
      __builtin_nontemporal_store(hi, reinterpret_cast<f32x4a*>(ab + t * 32 + f * 16 + 4));
    }
  }

  // ---- cross-wave O reduction via LDS float atomics ----
#pragma unroll
  for (int r = 0; r < 16; ++r) {
    const int row = (r & 3) + ((r >> 2) << 3) + (half << 2);
    atomicAdd(&ored[row * 68 + l31], oacc0[r]);
    atomicAdd(&ored[row * 68 + 32 + l31], oacc1[r]);
  }
  // lgkm-only barrier: do NOT drain vmcnt, the outstanding attn stores can
  // retire while the tiny O epilogue runs.
  asm volatile("s_waitcnt lgkmcnt(0)" ::: "memory");
  __builtin_amdgcn_s_barrier();
  __builtin_amdgcn_sched_barrier(0);

  const int orow = tid >> 3;
  const int oc = (tid & 7) * 8;
  const float iv = inv_lds[orow];
  f32x4 o0 = *reinterpret_cast<const f32x4a*>(ored + orow * 68 + oc);
  f32x4 o1 = *reinterpret_cast<const f32x4a*>(ored + orow * 68 + oc + 4);
#pragma unroll
  for (int jj = 0; jj < 4; ++jj) { o0[jj] *= iv; o1[jj] *= iv; }
  float* ob = outO + (((size_t)bh << 10) + q0 + orow) * D_DIM + oc;
  __builtin_nontemporal_store(o0, reinterpret_cast<f32x4a*>(ob));
  __builtin_nontemporal_store(o1, reinterpret_cast<f32x4a*>(ob + 4));
}

extern "C" void kernel_launch(void* const* d_in, const int* in_sizes, int n_in,
                              void* d_out, int out_size, void* d_ws, size_t ws_size,
                              hipStream_t stream) {
  (void)in_sizes; (void)n_in; (void)out_size; (void)d_ws; (void)ws_size;
  const float* Q = (const float*)d_in[0];
  const float* K = (const float*)d_in[1];
  const float* V = (const float*)d_in[2];
  const int*   M = (const int*)d_in[3];
  float* outO = (float*)d_out;
  float* outA = outO + (size_t)BHN * S_LEN * D_DIM;  // attn follows output, flat

  attn_kernel<<<dim3(BHN * (S_LEN / 32)), dim3(256), 0, stream>>>(Q, K, M, V, outO, outA);
}

// Round 3
// 469.584 us; speedup vs baseline: 1.0947x; 1.0777x over previous
//
#include <hip/hip_runtime.h>
#include <stdint.h>

typedef unsigned short u16;
typedef u16 u16x8 __attribute__((ext_vector_type(8)));
typedef u16x8 __attribute__((may_alias)) u16x8a;
typedef float f32x4 __attribute__((ext_vector_type(4)));
typedef f32x4 __attribute__((may_alias)) f32x4a;
typedef __bf16 bf16x8 __attribute__((ext_vector_type(8)));
typedef float f32x16 __attribute__((ext_vector_type(16)));

#define S_LEN 1024
#define D_DIM 64
#define BHN   64

// f32 -> bf16 via compiler cast: gfx950 emits v_cvt_pk_bf16_f32 (RNE, same
// rounding as software round-to-nearest-even bit-twiddle).
__device__ __forceinline__ bf16x8 cvt8(const float* p) {
  f32x4 a = *reinterpret_cast<const f32x4a*>(p);
  f32x4 b = *reinterpret_cast<const f32x4a*>(p + 4);
  bf16x8 r;
#pragma unroll
  for (int j = 0; j < 4; ++j) { r[j] = (__bf16)a[j]; r[4 + j] = (__bf16)b[j]; }
  return r;
}
__device__ __forceinline__ bf16x8 ldbf(const u16* p) {
  return __builtin_bit_cast(bf16x8, *reinterpret_cast<const u16x8a*>(p));
}

// ---------------- fused attention (fp32 in / fp32 out, bf16 MFMA inside) -------------
// block: 256 thr = 4 waves, one (bh, 32-row q tile). wave w owns k-cols [256w,256w+256).
// LDS (no aliasing):
//   [0, 20480)      ping-pong P-bounce tiles [2][4][32][40] u16 (per-wave, fence-only)
//   [20480, 29184)  O-reduce accumulator [32][68] f32 (ds_add_f32 atomics)
//   [29184, 29696)  rowsum [4][32] f32
//   [29696, 29824)  inv [32] f32
#define ORED_OFF   20480
#define RS_OFF     (ORED_OFF + 32 * 68 * 4)
#define INV_OFF    (RS_OFF + 512)
#define SMEM_BYTES (INV_OFF + 128)

// (256,3): live state is ~112 regs/lane (pfrag 64 + qa 16 + oacc 32 AGPR) +
// temps. Forcing 4 blocks/CU (<=128) spills to scratch: R1 measured +88 MB
// write traffic and 187->262 us. 3 blocks/CU spill-free is strictly better.
// NOTE (R2): __builtin_nontemporal_store on the attn stream caused 1.8x write
// amplification (WRITE 328->515 MB, +82 us): each 64B sector is assembled from
// two separate store instructions, which only merge on the cached path.
// Plain stores are mandatory here.
__global__ __launch_bounds__(256, 3) void attn_kernel(
    const float* __restrict__ Q, const float* __restrict__ K, const int* __restrict__ Mk,
    const float* __restrict__ V, float* __restrict__ outO, float* __restrict__ outA) {
  __shared__ __align__(16) char smem[SMEM_BYTES];
  const int tid = threadIdx.x;
  const int wave = tid >> 6, lane = tid & 63;
  const int l31 = lane & 31, half = lane >> 5;

  // XCD swizzle: ids congruent mod 8 share an XCD (round-robin dispatch).
  // The 32 q-tiles of ONE bh are time-contiguous on one XCD so K/V (512 KB)
  // stay L2-resident.
  const int id = blockIdx.x;                  // 0..2047
  const int xcd = id & 7, ord = id >> 3;      // ord: temporal order within XCD
  const int bh = xcd * 8 + (ord >> 5);
  const int q0 = (ord & 31) << 5;             // q-tile * 32

  u16* tbase = (u16*)smem;                    // ping-pong bounce tiles
  float* ored = (float*)(smem + ORED_OFF);    // [32][68] atomic O accumulator
  float* rs_lds = (float*)(smem + RS_OFF);    // [4][32]
  float* inv_lds = (float*)(smem + INV_OFF);  // [32]

  // zero the O accumulator (ordered before any ds_add by the rowsum barrier)
  for (int i = tid; i < 32 * 68; i += 256) ored[i] = 0.0f;

  // ---- Q A-fragments: lane holds Q[q0+l31][ks*16 + half*8 + j] (fp32 -> bf16) ----
  const float* qb = Q + (((size_t)bh << 10) + q0 + l31) * D_DIM + half * 8;
  bf16x8 qa[4];
#pragma unroll
  for (int ks = 0; ks < 4; ++ks) qa[ks] = cvt8(qb + ks * 16);

  const int colbase = wave * 256;
  const float* kb0 = K + ((size_t)bh << 10) * D_DIM + half * 8;
  const int* mrow = Mk + ((size_t)bh << 10) + colbase + l31;

  bf16x8 pfrag[16];  // wave's unnormalized exp(P) chunk [32 x 256] as A-frags
  float rs[16];
#pragma unroll
  for (int r = 0; r < 16; ++r) rs[r] = 0.0f;

  // ---- phase 1: QK^T -> exp -> A-layout frags. Bounce tile is PER-WAVE, so a
  // per-wave lgkmcnt fence replaces a __syncthreads (no 4-wave lockstep, no
  // vmcnt(0) drain of in-flight K loads).
#pragma unroll
  for (int t = 0; t < 8; ++t) {
    u16* tile = tbase + (((t & 1) << 2) + wave) * (32 * 40);
    const float* kb = kb0 + (size_t)(colbase + t * 32 + l31) * D_DIM;
    f32x16 acc = 0.0f;
#pragma unroll
    for (int ks = 0; ks < 4; ++ks) {
      bf16x8 kf = cvt8(kb + ks * 16);
      acc = __builtin_amdgcn_mfma_f32_32x32x16_bf16(qa[ks], kf, acc, 0, 0, 0);
    }
    const float mf = (mrow[t * 32] == 0) ? 0.0f : 1.0f;
#pragma unroll
    for (int r = 0; r < 16; ++r) {
      // score = acc/8 ; exp(score) = exp2(acc * 0.125*log2(e)); no max-sub needed
      float p = exp2f(acc[r] * 0.18033688f) * mf;
      __bf16 pb = (__bf16)p;
      rs[r] += (float)pb;  // bf16-consistent numerator/denominator
      const int row = (r & 3) + ((r >> 2) << 3) + (half << 2);  // C-layout row
      tile[row * 40 + l31] = __builtin_bit_cast(u16, pb);
    }
    // per-wave fence: bounce write -> bounce read (WAR across t handled by ping-pong)
    asm volatile("s_waitcnt lgkmcnt(0)" ::: "memory");
    __builtin_amdgcn_sched_barrier(0);
    pfrag[2 * t]     = ldbf(tile + l31 * 40 + half * 8);
    pfrag[2 * t + 1] = ldbf(tile + l31 * 40 + 16 + half * 8);
  }

  // ---- row sums: butterfly within 32-lane half, then cross-wave via LDS ----
#pragma unroll
  for (int r = 0; r < 16; ++r) {
    float s = rs[r];
#pragma unroll
    for (int m = 1; m < 32; m <<= 1) s += __shfl_xor(s, m, 64);
    rs[r] = s;
  }
  if (l31 == 0) {
#pragma unroll
    for (int r = 0; r < 16; ++r) {
      const int row = (r & 3) + ((r >> 2) << 3) + (half << 2);
      rs_lds[wave * 32 + row] = rs[r];
    }
  }
  __syncthreads();
  if (tid < 32) {
    float s = rs_lds[tid] + rs_lds[32 + tid] + rs_lds[64 + tid] + rs_lds[96 + tid];
    inv_lds[tid] = 1.0f / s;
  }
  __syncthreads();

  // ---- PV: O_partial[32x64]; B-frags scalar-loaded straight from global V
  // (L2-resident with the swizzle). ----
  f32x16 oacc0 = 0.0f, oacc1 = 0.0f;
  const float* vb = V + (((size_t)bh << 10) + colbase + half * 8) * D_DIM + l31;
#pragma unroll
  for (int kk = 0; kk < 16; ++kk) {
    bf16x8 b0, b1;
#pragma unroll
    for (int jj = 0; jj < 8; ++jj) {
      b0[jj] = (__bf16)vb[(kk * 16 + jj) * D_DIM];
      b1[jj] = (__bf16)vb[(kk * 16 + jj) * D_DIM + 32];
    }
    oacc0 = __builtin_amdgcn_mfma_f32_32x32x16_bf16(pfrag[kk], b0, oacc0, 0, 0, 0);
    oacc1 = __builtin_amdgcn_mfma_f32_32x32x16_bf16(pfrag[kk], b1, oacc1, 0, 0, 0);
  }

  // ---- attn write (fp32): direct from A-layout registers, 32B/lane runs,
  // plain cached stores (sectors merge in L2). ----
  const float myinv = inv_lds[l31];
  float* ab = outA + ((size_t)bh << 20) + ((size_t)(q0 + l31) << 10) + colbase + half * 8;
#pragma unroll
  for (int t = 0; t < 8; ++t) {
#pragma unroll
    for (int f = 0; f < 2; ++f) {
      bf16x8 pf = pfrag[2 * t + f];
      f32x4 lo, hi;
#pragma unroll
      for (int j = 0; j < 4; ++j) {
        lo[j] = (float)pf[j] * myinv;
        hi[j] = (float)pf[4 + j] * myinv;
      }
      *reinterpret_cast<f32x4a*>(ab + t * 32 + f * 16) = lo;
      *reinterpret_cast<f32x4a*>(ab + t * 32 + f * 16 + 4) = hi;
    }
  }

  // ---- cross-wave O reduction via LDS float atomics ----
#pragma unroll
  for (int r = 0; r < 16; ++r) {
    const int row = (r & 3) + ((r >> 2) << 3) + (half << 2);
    atomicAdd(&ored[row * 68 + l31], oacc0[r]);
    atomicAdd(&ored[row * 68 + 32 + l31], oacc1[r]);
  }
  // lgkm-only barrier: do NOT drain vmcnt, the outstanding attn stores can
  // retire while the tiny O epilogue runs.
  asm volatile("s_waitcnt lgkmcnt(0)" ::: "memory");
  __builtin_amdgcn_s_barrier();
  __builtin_amdgcn_sched_barrier(0);

  const int orow = tid >> 3;
  const int oc = (tid & 7) * 8;
  const float iv = inv_lds[orow];
  f32x4 o0 = *reinterpret_cast<const f32x4a*>(ored + orow * 68 + oc);
  f32x4 o1 = *reinterpret_cast<const f32x4a*>(ored + orow * 68 + oc + 4);
#pragma unroll
  for (int jj = 0; jj < 4; ++jj) { o0[jj] *= iv; o1[jj] *= iv; }
  float* ob = outO + (((size_t)bh << 10) + q0 + orow) * D_DIM + oc;
  *reinterpret_cast<f32x4a*>(ob) = o0;
  *reinterpret_cast<f32x4a*>(ob + 4) = o1;
}

extern "C" void kernel_launch(void* const* d_in, const int* in_sizes, int n_in,
                              void* d_out, int out_size, void* d_ws, size_t ws_size,
                              hipStream_t stream) {
  (void)in_sizes; (void)n_in; (void)out_size; (void)d_ws; (void)ws_size;
  const float* Q = (const float*)d_in[0];
  const float* K = (const float*)d_in[1];
  const float* V = (const float*)d_in[2];
  const int*   M = (const int*)d_in[3];
  float* outO = (float*)d_out;
  float* outA = outO + (size_t)BHN * S_LEN * D_DIM;  // attn follows output, flat

  attn_kernel<<<dim3(BHN * (S_LEN / 32)), dim3(256), 0, stream>>>(Q, K, M, V, outO, outA);
}